// Round 3
// baseline (638.227 us; speedup 1.0000x reference)
//
#include <hip/hip_runtime.h>
#include <hip/hip_fp16.h>
#include <cstdint>

#define P2 2654435761u
#define P3 805459861u
#define HMASK 524287u

typedef float f2v __attribute__((ext_vector_type(2)));

// int(16 * exp((ln2048-ln16)/15)**l), hand-verified vs IEEE-double reference.
// res[7]=153 (153.987), res[15]=2048 (2048.0000000000036, min-clamped).
__constant__ int c_res[16] = {16, 22, 30, 42, 58, 80, 111, 153,
                              212, 294, 406, 561, 776, 1072, 1482, 2048};
// dense levels 0..5 (res 16..80); cumulative cell offsets and total
__constant__ uint32_t c_goff[6] = {0u, 4096u, 14744u, 41744u, 115832u, 310944u};
#define DENSE_CELLS 822944u
#define NDENSE 6

// Build dense per-level grids: cell (l,x,y,z) holds fp16 features of corner z
// (lo 4B) and corner z+1 clamped (hi 4B). Layout: cell = goff[l]+(x*r+y)*r+z,
// 8 B/cell. 823K cells total (~5 us) -- rebuilt every launch (ws re-poisoned).
__global__ __launch_bounds__(256) void build_grids(const float2* __restrict__ tbl,
                                                   uint32_t* __restrict__ grid)
{
    uint32_t t = blockIdx.x * 256u + threadIdx.x;
    if (t >= DENSE_CELLS) return;
    int l = 0;
    #pragma unroll
    for (int j = 1; j < NDENSE; ++j) l += (t >= c_goff[j]);
    uint32_t idx = t - c_goff[l];
    uint32_t r = (uint32_t)c_res[l];
    uint32_t zz = idx % r;
    uint32_t rem = idx / r;
    uint32_t yy = rem % r;
    uint32_t xx = rem / r;
    float2 f = tbl[(xx ^ (yy * P2) ^ (zz * P3)) & HMASK];
    __half2 hv = __floats2half2_rn(f.x, f.y);
    uint32_t packed = *reinterpret_cast<uint32_t*>(&hv);
    grid[2u * t] = packed;                         // (x,y,z).lo
    if (zz > 0u)       grid[2u * (t - 1u) + 1u] = packed;  // (x,y,z-1).hi
    if (zz == r - 1u)  grid[2u * t + 1u] = packed;         // clamped top corner
}

__device__ inline float2 zblend(uint2 q, float uz, float wz) {
    __half2 a = *reinterpret_cast<__half2*>(&q.x);
    __half2 b = *reinterpret_cast<__half2*>(&q.y);
    float2 fa = __half22float2(a), fb = __half22float2(b);
    return make_float2(uz * fa.x + wz * fb.x, uz * fa.y + wz * fb.y);
}

// One thread per (point, level), t = i*16 + l (point-major: coalesced store).
__global__ __launch_bounds__(256) void hash_enc_main(
    const float* __restrict__ pos, const float2* __restrict__ tbl,
    const uint32_t* __restrict__ grid, float2* __restrict__ out, int n, int K)
{
    __shared__ int sres[16];
    __shared__ uint32_t soff[8];
    if (threadIdx.x < 16) sres[threadIdx.x] = c_res[threadIdx.x];
    if (threadIdx.x < NDENSE) soff[threadIdx.x] = c_goff[threadIdx.x];
    __syncthreads();

    int t = blockIdx.x * 256 + threadIdx.x;
    int i = t >> 4;
    int l = t & 15;
    if (i >= n) return;

    // 16 consecutive lanes share these 12 bytes -> coalesced/L1 broadcast
    float px = (pos[3 * i + 0] + 1.0f) * 0.5f;
    float py = (pos[3 * i + 1] + 1.0f) * 0.5f;
    float pz = (pos[3 * i + 2] + 1.0f) * 0.5f;

    const int rm1 = sres[l] - 1;
    const float rf = (float)rm1;
    float sx = px * rf, sy = py * rf, sz = pz * rf;
    float fx = floorf(sx), fy = floorf(sy), fz = floorf(sz);
    float wx = sx - fx, wy = sy - fy, wz = sz - fz;
    // p in [0,1] exactly -> x0,y0,z0 already in [0, rm1]; only +1 needs clamp
    int x0 = (int)fx, y0 = (int)fy, z0 = (int)fz;
    float ux = 1.0f - wx, uy = 1.0f - wy, uz = 1.0f - wz;
    float w00 = ux * uy, w01 = ux * wy, w10 = wx * uy, w11 = wx * wy;

    float f0, f1;
    if (l < K) {
        // dense path: 4 aligned 8B loads (z-pair packed), separable blend
        uint32_t r = (uint32_t)(rm1 + 1);
        uint32_t cell = soff[l] + ((uint32_t)x0 * r + (uint32_t)y0) * r + (uint32_t)z0;
        uint32_t dy = (y0 < rm1) ? r : 0u;
        uint32_t dx = (x0 < rm1) ? r * r : 0u;
        const uint2* g2 = reinterpret_cast<const uint2*>(grid);
        uint2 q00 = g2[cell];
        uint2 q01 = g2[cell + dy];
        uint2 q10 = g2[cell + dx];
        uint2 q11 = g2[cell + dx + dy];
        float2 v00 = zblend(q00, uz, wz);
        float2 v01 = zblend(q01, uz, wz);
        float2 v10 = zblend(q10, uz, wz);
        float2 v11 = zblend(q11, uz, wz);
        f0 = w00 * v00.x + w01 * v01.x + w10 * v10.x + w11 * v11.x;
        f1 = w00 * v00.y + w01 * v01.y + w10 * v10.y + w11 * v11.y;
    } else {
        // scattered path: 8 independent hashed gathers (table is L2-resident)
        int x1c = min(x0 + 1, rm1), y1c = min(y0 + 1, rm1), z1c = min(z0 + 1, rm1);
        uint32_t hx0 = (uint32_t)x0,        hx1 = (uint32_t)x1c;
        uint32_t hy0 = (uint32_t)y0  * P2,  hy1 = (uint32_t)y1c * P2;
        uint32_t hz0 = (uint32_t)z0  * P3,  hz1 = (uint32_t)z1c * P3;
        float2 c000 = tbl[(hx0 ^ hy0 ^ hz0) & HMASK];
        float2 c001 = tbl[(hx0 ^ hy0 ^ hz1) & HMASK];
        float2 c010 = tbl[(hx0 ^ hy1 ^ hz0) & HMASK];
        float2 c011 = tbl[(hx0 ^ hy1 ^ hz1) & HMASK];
        float2 c100 = tbl[(hx1 ^ hy0 ^ hz0) & HMASK];
        float2 c101 = tbl[(hx1 ^ hy0 ^ hz1) & HMASK];
        float2 c110 = tbl[(hx1 ^ hy1 ^ hz0) & HMASK];
        float2 c111 = tbl[(hx1 ^ hy1 ^ hz1) & HMASK];
        f0  = (w00 * uz) * c000.x; f1  = (w00 * uz) * c000.y;
        f0 += (w00 * wz) * c001.x; f1 += (w00 * wz) * c001.y;
        f0 += (w01 * uz) * c010.x; f1 += (w01 * uz) * c010.y;
        f0 += (w01 * wz) * c011.x; f1 += (w01 * wz) * c011.y;
        f0 += (w10 * uz) * c100.x; f1 += (w10 * uz) * c100.y;
        f0 += (w10 * wz) * c101.x; f1 += (w10 * wz) * c101.y;
        f0 += (w11 * uz) * c110.x; f1 += (w11 * uz) * c110.y;
        f0 += (w11 * wz) * c111.x; f1 += (w11 * wz) * c111.y;
    }

    // non-temporal: keep the 131 MB output stream out of L2 (table residency)
    f2v v; v.x = f0; v.y = f1;
    __builtin_nontemporal_store(v, reinterpret_cast<f2v*>(out) + t);
}

extern "C" void kernel_launch(void* const* d_in, const int* in_sizes, int n_in,
                              void* d_out, int out_size, void* d_ws, size_t ws_size,
                              hipStream_t stream) {
    const float* pos = (const float*)d_in[0];
    const float2* tbl = (const float2*)d_in[1];
    float2* out = (float2*)d_out;
    int n = in_sizes[0] / 3;

    int K = (ws_size >= (size_t)DENSE_CELLS * 8u) ? NDENSE : 0;
    if (K) {
        build_grids<<<(DENSE_CELLS + 255u) / 256u, 256, 0, stream>>>(
            tbl, (uint32_t*)d_ws);
    }
    long long total = (long long)n * 16;
    hash_enc_main<<<(unsigned)((total + 255) / 256), 256, 0, stream>>>(
        pos, tbl, (const uint32_t*)d_ws, out, n, K);
}